// Round 8
// baseline (109.757 us; speedup 1.0000x reference)
//
#include <hip/hip_runtime.h>
#include <hip/hip_bf16.h>
#include <math.h>

#define C 8
#define K 128
#define S 64
#define L 2048
#define NB 64
#define W (L - S + 1)   // 1985
#define TW 64
#define NTW 32
#define XCS 144         // xcop stride shorts: 72 dw = 8 banks mod 32 -> conflict-free b128
#define XFS 136         // fp32 x scratch stride (128 data + 8 zero pad; 8 mod 32 dw)

typedef __attribute__((ext_vector_type(8))) short bf16x8;
typedef __attribute__((ext_vector_type(4))) float f32x4;

__device__ __forceinline__ unsigned short f2bf(float f) {
  unsigned int u = __float_as_uint(f);
  u += 0x7FFFu + ((u >> 16) & 1u);   // RNE
  return (unsigned short)(u >> 16);
}

// packed f32x2 -> bf16x2 (v_cvt_pk_bf16_f32 on gfx950)
__device__ __forceinline__ unsigned int pkbf(float a, float b) {
  __hip_bfloat162 h = __float22bfloat162_rn(make_float2(a, b));
  return *reinterpret_cast<unsigned int*>(&h);
}

// prep: z-normalize shapelets -> bf16 * (-2), B-fragment order grouped by
// CHANNEL (16 KB contiguous per c); init out to +inf. sum(z^2) == S == 64
// exactly (population z-norm) -> no per-k sqs needed. UNCHANGED since R1.
__global__ __launch_bounds__(256) void prep_kernel(const float* __restrict__ sh,
                                                   unsigned short* __restrict__ shzB,
                                                   float* __restrict__ out) {
  int tid = blockIdx.x * 256 + threadIdx.x;
  if (tid < NB * K) out[tid] = __int_as_float(0x7F800000);
  int gid = blockIdx.x * 4 + (threadIdx.x >> 6);  // c*K + k
  int lane = threadIdx.x & 63;                    // = s
  float v = sh[(size_t)gid * S + lane];
  float s1 = v, s2 = v * v;
#pragma unroll
  for (int off = 32; off > 0; off >>= 1) {
    s1 += __shfl_down(s1, off);
    s2 += __shfl_down(s2, off);
  }
  s1 = __shfl(s1, 0);
  s2 = __shfl(s2, 0);
  float mu = s1 * (1.0f / S);
  float sd = sqrtf(fmaxf(s2 * (1.0f / S) - mu * mu, 0.0f));
  float z = (v - mu) / sd;
  int c = gid >> 7, k = gid & (K - 1), s = lane;
  // layout: [c][k>>6][((k>>4)&3)*2 + (s>>5)][lane'=((s>>3)&3)*16+(k&15)][s&7]
  int idx = c * 8192 + (k >> 6) * 4096 + ((((k >> 4) & 3) * 2) + (s >> 5)) * 512 +
            ((((s >> 3) & 3) * 16 + (k & 15)) * 8) + (s & 7);
  shzB[idx] = f2bf(-2.0f * z);   // bake the -2 of d2 = (sqx + 64) - 2*cross
}

// One wt-subtile: 4 MFMAs (2 kt x 2 halves) into P[0..1] (all indices literal)
#define WT_COMPUTE(WT, P)                                                     \
  {                                                                           \
    bf16x8 x0 = *(const bf16x8*)(xc + abase + (WT) * 16);                     \
    bf16x8 x1 = *(const bf16x8*)(xc + abase + (WT) * 16 + 32);                \
    f32x4 ai = *(const f32x4*)&sqx[c][(WT) * 16 + quad * 4];                  \
    P[0] = __builtin_amdgcn_mfma_f32_16x16x32_bf16(x0, Bc[0], ai, 0, 0, 0);   \
    P[1] = __builtin_amdgcn_mfma_f32_16x16x32_bf16(x0, Bc[2], ai, 0, 0, 0);   \
    P[0] = __builtin_amdgcn_mfma_f32_16x16x32_bf16(x1, Bc[1], P[0], 0, 0, 0); \
    P[1] = __builtin_amdgcn_mfma_f32_16x16x32_bf16(x1, Bc[3], P[1], 0, 0, 0); \
  }

// trans epilogue of one wt-subtile (literal WT -> static dsum indexing)
#define WT_SQRT(WT, P)                                                        \
  {                                                                           \
    _Pragma("unroll")                                                         \
    for (int i = 0; i < 4; ++i) {                                             \
      dsum[0][WT][i] += __builtin_amdgcn_sqrtf(__builtin_fabsf(P[0][i]));     \
      dsum[1][WT][i] += __builtin_amdgcn_sqrtf(__builtin_fabsf(P[1][i]));     \
    }                                                                         \
  }

// main: block = 64w x 128k, 256 threads = 4 waves, wave tile 64w x 32k
// (kgrp = wave selects a 32k quarter; all waves share the same 64 w's).
// R7 post-mortem: live-state reduction -> 3 waves/SIMD bought 8% — the
// binder is trans-issue work at ~45-50% feed; the only lever that moved
// time in 8 rounds is resident decorrelated waves/SIMD. R8 pushes that
// axis hard: half the wave tile (dsum 32 + Bc 16 + pA/pB 16 ~ 98 VGPR ->
// 5 waves/SIMD), LDS 24.3 KB (6 blocks/CU), 2x the wave count at half
// work each, channel-ring stagger retained. Arithmetic chain per output
// unchanged -> absmax 0.5. Tripwire: WRITE_SIZE must stay ~1 MB.
__global__ __launch_bounds__(256, 4) void main_kernel(const float* __restrict__ x,
                                                      const unsigned short* __restrict__ shzB,
                                                      int* __restrict__ out) {
  __shared__ __align__(16) unsigned short xcop[C][8][XCS]; // 18 KB: 8 shifted copies
  __shared__ __align__(16) float sqx[C][TW];               // 2 KB (pre-biased +64)
  __shared__ __align__(16) float xf[C][XFS];               // 4.25 KB fp32 x scratch

  const int t = threadIdx.x;
  const int lane = t & 63;
  const int wave = t >> 6;     // 0..3 = kgrp (32k quarter)
  const int kgrp = wave;
  const int col = lane & 15;
  const int quad = lane >> 4;
  const int n = blockIdx.y;
  const int w0 = blockIdx.x * TW;
  const float* xn = x + (size_t)n * C * L;
  // this wave's B-fragment stream: 4 x 1KB contiguous chunks per channel
  // chunk base for the 32k quarter: (kgrp>>1)*8 + (kgrp&1)*4
  const unsigned short* bw =
      shzB + ((kgrp >> 1) * 8 + (kgrp & 1) * 4) * 512 + lane * 8;
  // phase-stagger start channel (wave-uniform SGPR; decorrelates waves/blocks)
  const int cbase = (2 * wave + blockIdx.x + blockIdx.y) & 7;

  // ---- stage fp32 x segment into xf (2 ch/wave, float4/lane, 127 floats) ----
  float* xfp = &xf[0][0];
#pragma unroll
  for (int cc = 0; cc < 2; ++cc) {
    const int c = wave * 2 + cc;
    const int e = lane * 4;
    float4 v; v.x = v.y = v.z = v.w = 0.0f;
    if (lane < 32) {
      int g = w0 + e;
      if (g + 3 < L) {
        v = *(const float4*)(xn + c * L + g);
      } else {  // last w-tile tail; feeds masked windows only
        v.x = (g + 0 < L) ? xn[c * L + g + 0] : 0.0f;
        v.y = (g + 1 < L) ? xn[c * L + g + 1] : 0.0f;
        v.z = (g + 2 < L) ? xn[c * L + g + 2] : 0.0f;
        v.w = (g + 3 < L) ? xn[c * L + g + 3] : 0.0f;
      }
    }
    if (lane < 34) *(float4*)&xfp[c * XFS + e] = v;   // lanes 32,33 zero-pad tail
  }
  __syncthreads();

  // ---- build 8 shifted bf16 copies (2 ch/wave; r=lane>>3; 8 dwords/lane/ch) ----
#pragma unroll
  for (int cc = 0; cc < 2; ++cc) {
    const int cb = wave * 2 + cc;
    const int rb = lane >> 3;         // 0..7
    const int c8 = lane & 7;
    const float* xr = xfp + cb * XFS;
#pragma unroll
    for (int j = 0; j < 8; ++j) {
      int i = (c8 + j * 8) * 2;       // 0..126 even
      *(unsigned int*)&xcop[cb][rb][i] = pkbf(xr[i + rb], xr[i + rb + 1]);
    }
  }
  // ---- fp32 sqx (+64 bias = sum(z^2)): 2 ch/wave, 1 w/lane, 64 FMAs ----
#pragma unroll
  for (int cc = 0; cc < 2; ++cc) {
    const int c = wave * 2 + cc;
    const float* xr = xfp + c * XFS + lane;
    float p0 = 0.f, p1 = 0.f, p2 = 0.f, p3 = 0.f;
#pragma unroll
    for (int si = 0; si < S; si += 4) {
      float v0 = xr[si], v1 = xr[si + 1], v2 = xr[si + 2], v3 = xr[si + 3];
      p0 = fmaf(v0, v0, p0); p1 = fmaf(v1, v1, p1);
      p2 = fmaf(v2, v2, p2); p3 = fmaf(v3, v3, p3);
    }
    sqx[c][lane] = 64.0f + (p0 + p1) + (p2 + p3);
  }
  __syncthreads();  // xcop + sqx ready; NO barriers after this point

  const f32x4 z4 = {0.0f, 0.0f, 0.0f, 0.0f};
  f32x4 dsum[2][4];   // [ktile][wtile]
#pragma unroll
  for (int kt = 0; kt < 2; ++kt)
#pragma unroll
    for (int wt = 0; wt < 4; ++wt) dsum[kt][wt] = z4;

  const int r8 = col & 7;
  const int abase = (col - r8) + quad * 8;  // multiple of 8 -> b128 aligned

  for (int ci = 0; ci < C; ++ci) {
    const int c = (cbase + ci) & 7;   // wave-uniform (SGPR arithmetic)

    // B fragments for this channel's 32k quarter: 4 coalesced dwordx4 from L1/L2
    bf16x8 Bc[4];
#pragma unroll
    for (int i = 0; i < 4; ++i)
      Bc[i] = *(const bf16x8*)(bw + c * 8192 + i * 512);

    const unsigned short* xc = &xcop[c][r8][0];

    // wt-granularity alternation: MFMA(wt+1) drains while sqrt(wt) runs.
    f32x4 pA[2], pB[2];
    WT_COMPUTE(0, pA)
    WT_COMPUTE(1, pB)
    WT_SQRT(0, pA)
    WT_COMPUTE(2, pA)
    WT_SQRT(1, pB)
    WT_COMPUTE(3, pB)
    WT_SQRT(2, pA)
    WT_SQRT(3, pB)
  }

  // min over w (regs -> quad shuffles), one atomicMin per (k-tile, lane col)
  const float INF = __int_as_float(0x7F800000);
#pragma unroll
  for (int kt = 0; kt < 2; ++kt) {
    float mv = INF;
#pragma unroll
    for (int wt = 0; wt < 4; ++wt)
#pragma unroll
      for (int i = 0; i < 4; ++i) {
        int w = w0 + wt * 16 + quad * 4 + i;
        mv = (w < W) ? fminf(mv, dsum[kt][wt][i]) : mv;
      }
    mv = fminf(mv, __shfl_xor(mv, 16));
    mv = fminf(mv, __shfl_xor(mv, 32));
    if (quad == 0)
      atomicMin(&out[n * K + kgrp * 32 + kt * 16 + col], __float_as_int(mv));
  }
}

extern "C" void kernel_launch(void* const* d_in, const int* in_sizes, int n_in,
                              void* d_out, int out_size, void* d_ws, size_t ws_size,
                              hipStream_t stream) {
  const float* x = (const float*)d_in[0];    // (64, 8, 2048) fp32
  const float* sh = (const float*)d_in[1];   // (8, 128, 64) fp32
  float* out = (float*)d_out;                // (64, 1, 128) fp32
  unsigned short* shzB = (unsigned short*)d_ws;  // 128 KB bf16 B-frag layout (scaled -2)

  prep_kernel<<<256, 256, 0, stream>>>(sh, shzB, out);
  main_kernel<<<dim3(NTW, NB), 256, 0, stream>>>(x, shzB, (int*)out);
}

// Round 9
// 105.597 us; speedup vs baseline: 1.0394x; 1.0394x over previous
//
#include <hip/hip_runtime.h>
#include <hip/hip_bf16.h>
#include <math.h>

#define C 8
#define K 128
#define S 64
#define L 2048
#define NB 64
#define W (L - S + 1)   // 1985
#define TW 128
#define NTW 16
#define XCS 208         // xcop stride shorts: 104 dw = 8 banks mod 32 -> conflict-free b128
#define XFS 200         // fp32 x scratch stride (192 data + 8 zero pad)
#define SW 72           // d2 slab stride (dwords); k-major [k][w], b128-aligned

typedef __attribute__((ext_vector_type(8))) short bf16x8;
typedef __attribute__((ext_vector_type(4))) float f32x4;

__device__ __forceinline__ unsigned short f2bf(float f) {
  unsigned int u = __float_as_uint(f);
  u += 0x7FFFu + ((u >> 16) & 1u);   // RNE
  return (unsigned short)(u >> 16);
}

// packed f32x2 -> bf16x2 (v_cvt_pk_bf16_f32 on gfx950)
__device__ __forceinline__ unsigned int pkbf(float a, float b) {
  __hip_bfloat162 h = __float22bfloat162_rn(make_float2(a, b));
  return *reinterpret_cast<unsigned int*>(&h);
}

// prep: z-normalize shapelets -> bf16 * (-2), B-fragment order grouped by
// CHANNEL (16 KB contiguous per c); init out to +inf. sum(z^2) == S == 64
// exactly (population z-norm) -> no per-k sqs needed. UNCHANGED since R1.
__global__ __launch_bounds__(256) void prep_kernel(const float* __restrict__ sh,
                                                   unsigned short* __restrict__ shzB,
                                                   float* __restrict__ out) {
  int tid = blockIdx.x * 256 + threadIdx.x;
  if (tid < NB * K) out[tid] = __int_as_float(0x7F800000);
  int gid = blockIdx.x * 4 + (threadIdx.x >> 6);  // c*K + k
  int lane = threadIdx.x & 63;                    // = s
  float v = sh[(size_t)gid * S + lane];
  float s1 = v, s2 = v * v;
#pragma unroll
  for (int off = 32; off > 0; off >>= 1) {
    s1 += __shfl_down(s1, off);
    s2 += __shfl_down(s2, off);
  }
  s1 = __shfl(s1, 0);
  s2 = __shfl(s2, 0);
  float mu = s1 * (1.0f / S);
  float sd = sqrtf(fmaxf(s2 * (1.0f / S) - mu * mu, 0.0f));
  float z = (v - mu) / sd;
  int c = gid >> 7, k = gid & (K - 1), s = lane;
  // layout: [c][k>>6][((k>>4)&3)*2 + (s>>5)][lane'=((s>>3)&3)*16+(k&15)][s&7]
  int idx = c * 8192 + (k >> 6) * 4096 + ((((k >> 4) & 3) * 2) + (s >> 5)) * 512 +
            ((((s >> 3) & 3) * 16 + (k & 15)) * 8) + (s & 7);
  shzB[idx] = f2bf(-2.0f * z);   // bake the -2 of d2 = (sqx + 64) - 2*cross
}

// Producer half-phase: 16 MFMAs (32w x 64k, K=64) -> k-major slab[SLOT].
// C-fragment = 4 consecutive w-rows at one k-col -> single b128 store.
#define PRODUCE(H, SLOT)                                                        \
  {                                                                             \
    const unsigned short* xc = &xcop[c][r8][0];                                 \
    const int wb = (H) * 64 + pw2 * 32;                                         \
    _Pragma("unroll")                                                           \
    for (int wt = 0; wt < 2; ++wt) {                                            \
      f32x4 ai = *(const f32x4*)&sqx[c][wb + wt * 16 + quad * 4];               \
      bf16x8 x0 = *(const bf16x8*)(xc + alane + wb + wt * 16);                  \
      bf16x8 x1 = *(const bf16x8*)(xc + alane + wb + wt * 16 + 32);             \
      _Pragma("unroll")                                                         \
      for (int kt = 0; kt < 4; ++kt) {                                          \
        f32x4 acc =                                                             \
            __builtin_amdgcn_mfma_f32_16x16x32_bf16(x0, Bc[2 * kt], ai, 0, 0, 0);\
        acc = __builtin_amdgcn_mfma_f32_16x16x32_bf16(x1, Bc[2 * kt + 1], acc,  \
                                                      0, 0, 0);                 \
        *(f32x4*)&slab[SLOT][pk * 64 + kt * 16 + col]                           \
                           [pw2 * 32 + wt * 16 + quad * 4] = acc;               \
      }                                                                         \
    }                                                                           \
  }

// Consumer half-phase: 8 b128 reads (64w x 32k worth of d2) -> 32 sqrt+add.
// All indices literal after unroll (rule-#20 safe).
#define CONSUME(SLOT, DS)                                                       \
  {                                                                             \
    f32x4 r[4][2];                                                              \
    _Pragma("unroll")                                                           \
    for (int wt = 0; wt < 4; ++wt)                                              \
      _Pragma("unroll")                                                         \
      for (int kl = 0; kl < 2; ++kl)                                            \
        r[wt][kl] = *(const f32x4*)&slab[SLOT][q * 32 + kl * 16 + col]          \
                                             [wt * 16 + quad * 4];              \
    _Pragma("unroll")                                                           \
    for (int wt = 0; wt < 4; ++wt)                                              \
      _Pragma("unroll")                                                         \
      for (int kl = 0; kl < 2; ++kl)                                            \
        _Pragma("unroll")                                                       \
        for (int i = 0; i < 4; ++i)                                             \
          DS[wt][kl][i] +=                                                      \
              __builtin_amdgcn_sqrtf(__builtin_fabsf(r[wt][kl][i]));            \
  }

// main: block = 128w x 128k, 512 threads = 8 waves, PRODUCER/CONSUMER split.
// R8 post-mortem: geometry change re-triggered scratch (FETCH 64MB/WRITE
// 117MB) — reverted. Standing result: homogeneous waves pin at 39-42us
// because every wave serializes {loads -> MFMA -> 1000cy trans burst} and
// co-resident same-role waves can't keep the trans pipe fed (~35-50%).
// R9 = wave specialization: waves 0-3 produce d2 tiles (MFMA only, sqx as
// free C-operand), waves 4-7 consume (pure ds_read->sqrt->add streams).
// HW round-robin puts producer i + consumer i on SIMD i -> complementary
// pipes co-resident. d2 passes via ping-pong k-major LDS slab [128k][72w]:
// the 16x16 C-fragment (4 consecutive w, one k) is ONE b128 store/read.
// 1 barrier per half-channel (17 total); producers prefetch Bc before each
// barrier so VMEM latency hides under the barrier wait. Producer phase
// (~400cy) < consumer phase (~600cy, 89% trans) -> consumers never starve.
// Same per-output arithmetic chain (ai -> x0*B -> x1*B, sqrt(fabs),
// commutative channel ring) -> absmax ~0.5.
// Tripwire: WRITE_SIZE ~1MB, FETCH ~4MB (else scratch/spill -> void).
__global__ __launch_bounds__(512, 1) void main_kernel(const float* __restrict__ x,
                                                      const unsigned short* __restrict__ shzB,
                                                      int* __restrict__ out) {
  __shared__ __align__(16) float slab[2][K][SW];            // 72 KB d2 ping-pong
  __shared__ __align__(16) unsigned short xcop[C][8][XCS];  // 26 KB shifted copies
  __shared__ __align__(16) float sqx[C][TW];                // 4 KB (pre-biased +64)

  const int t = threadIdx.x;
  const int lane = t & 63;
  const int wave = t >> 6;     // 0..7
  const int col = lane & 15;
  const int quad = lane >> 4;
  const int n = blockIdx.y;
  const int w0 = blockIdx.x * TW;
  const float* xn = x + (size_t)n * C * L;
  const int cbase = (blockIdx.x + 3 * blockIdx.y) & 7;   // per-block ring stagger

  // ---- prologue (R0 8-wave pattern): stage fp32 x into slab-as-scratch ----
  float* xfp = &slab[0][0][0];   // 8 ch x XFS floats = 6.4 KB << 72 KB
  {
    const int c = wave;
    const int e = lane * 4;
    float4 v; v.x = v.y = v.z = v.w = 0.0f;
    if (lane < 48) {
      int g = w0 + e;
      if (g + 3 < L) {
        v = *(const float4*)(xn + c * L + g);
      } else {  // last w-tile tail; feeds masked windows only
        v.x = (g + 0 < L) ? xn[c * L + g + 0] : 0.0f;
        v.y = (g + 1 < L) ? xn[c * L + g + 1] : 0.0f;
        v.z = (g + 2 < L) ? xn[c * L + g + 2] : 0.0f;
        v.w = (g + 3 < L) ? xn[c * L + g + 3] : 0.0f;
      }
    }
    if (lane < 50) *(float4*)&xfp[c * XFS + e] = v;   // lanes 48,49 zero-pad tail
  }
  __syncthreads();

  // ---- build 8 shifted bf16 copies (1 ch/wave; r=lane>>3; 12 dwords/lane) ----
  {
    const int cb = wave;
    const int rb = lane >> 3;         // 0..7
    const int c8 = lane & 7;
    const float* xr = xfp + cb * XFS;
#pragma unroll
    for (int j = 0; j < 12; ++j) {
      int i = (c8 + j * 8) * 2;       // 0..190 even
      *(unsigned int*)&xcop[cb][rb][i] = pkbf(xr[i + rb], xr[i + rb + 1]);
    }
  }
  // ---- sliding-window fp32 sqx (+64 bias = sum(z^2)): 1 ch/wave, 2 w/lane ----
  {
    const int c = wave, wl = lane * 2;
    const float* xr = xfp + c * XFS;
    float p0 = 0.f, p1 = 0.f, p2 = 0.f, p3 = 0.f;
#pragma unroll
    for (int si = 0; si < S; si += 4) {
      float v0 = xr[wl + si], v1 = xr[wl + si + 1], v2 = xr[wl + si + 2], v3 = xr[wl + si + 3];
      p0 = fmaf(v0, v0, p0); p1 = fmaf(v1, v1, p1);
      p2 = fmaf(v2, v2, p2); p3 = fmaf(v3, v3, p3);
    }
    float s0 = 64.0f + (p0 + p1) + (p2 + p3);
    sqx[c][wl] = s0;
    float a = xr[wl + S], b = xr[wl];
    sqx[c][wl + 1] = s0 + a * a - b * b;
  }
  // NOTE: no sync here — the first loop barrier separates xf/xcop/sqx writes
  // from producer xcop/sqx reads AND from slab overwrite.

  const int r8 = col & 7;
  const int alane = (col - r8) + quad * 8;  // A-frag lane addressing (b128-aligned)

  // producer role constants (waves 0-3)
  const int pk = wave >> 1;    // k-half 0/1
  const int pw2 = wave & 1;    // 32-row sub-offset within the w-half
  const unsigned short* bwp = shzB + pk * 4096 + lane * 8;

  // consumer role constants (waves 4-7)
  const int q = wave & 3;      // k-quarter
  const f32x4 z4 = {0.0f, 0.0f, 0.0f, 0.0f};
  f32x4 ds0[4][2], ds1[4][2];  // [wt][ktl] for w-half 0 / 1
#pragma unroll
  for (int wt = 0; wt < 4; ++wt)
#pragma unroll
    for (int kl = 0; kl < 2; ++kl) { ds0[wt][kl] = z4; ds1[wt][kl] = z4; }

  if (wave >= 4) __builtin_amdgcn_s_setprio(1);  // consumers win issue arbitration

  for (int ci = 0; ci < 8; ++ci) {
    const int c = (cbase + ci) & 7;   // wave-uniform ring

    // Bc prefetch BEFORE the barrier: VMEM latency hides under barrier wait
    bf16x8 Bc[8];
    if (wave < 4) {
#pragma unroll
      for (int i = 0; i < 8; ++i)
        Bc[i] = *(const bf16x8*)(bwp + c * 8192 + i * 512);
    }

    __syncthreads();   // slab[0] drained (phase ci-1,h=0 consumed) / Bc in flight
    if (wave < 4) {
      PRODUCE(0, 0)
    } else if (ci > 0) {
      CONSUME(1, ds1)  // previous channel's h=1 half
    }

    __syncthreads();   // slab[0] ready; slab[1] drained
    if (wave < 4) {
      PRODUCE(1, 1)
    } else {
      CONSUME(0, ds0)  // this channel's h=0 half
    }
  }
  __syncthreads();     // final slab[1] ready
  if (wave >= 4) {
    CONSUME(1, ds1)    // last channel's h=1 half

    // min over w (regs -> quad shuffles), one atomicMin per (ktl, lane col)
    const float INF = __int_as_float(0x7F800000);
#pragma unroll
    for (int kl = 0; kl < 2; ++kl) {
      float mv = INF;
#pragma unroll
      for (int wt = 0; wt < 4; ++wt)
#pragma unroll
        for (int i = 0; i < 4; ++i) {
          int wA = w0 + wt * 16 + quad * 4 + i;        // h=0 half
          int wB = wA + 64;                             // h=1 half
          mv = (wA < W) ? fminf(mv, ds0[wt][kl][i]) : mv;
          mv = (wB < W) ? fminf(mv, ds1[wt][kl][i]) : mv;
        }
      mv = fminf(mv, __shfl_xor(mv, 16));
      mv = fminf(mv, __shfl_xor(mv, 32));
      if (quad == 0)
        atomicMin(&out[n * K + q * 32 + kl * 16 + col], __float_as_int(mv));
    }
  }
}

extern "C" void kernel_launch(void* const* d_in, const int* in_sizes, int n_in,
                              void* d_out, int out_size, void* d_ws, size_t ws_size,
                              hipStream_t stream) {
  const float* x = (const float*)d_in[0];    // (64, 8, 2048) fp32
  const float* sh = (const float*)d_in[1];   // (8, 128, 64) fp32
  float* out = (float*)d_out;                // (64, 1, 128) fp32
  unsigned short* shzB = (unsigned short*)d_ws;  // 128 KB bf16 B-frag layout (scaled -2)

  prep_kernel<<<256, 256, 0, stream>>>(sh, shzB, out);
  main_kernel<<<dim3(NTW, NB), 512, 0, stream>>>(x, shzB, (int*)out);
}

// Round 10
// 94.379 us; speedup vs baseline: 1.1629x; 1.1189x over previous
//
#include <hip/hip_runtime.h>
#include <hip/hip_bf16.h>
#include <math.h>

#define C 8
#define K 128
#define S 64
#define L 2048
#define NB 64
#define W (L - S + 1)   // 1985
#define TW 128
#define NTW 16
#define XCS 208         // xcop stride shorts: 104 dw = 8 banks mod 32 -> conflict-free b128
#define XFS 200         // fp32 x scratch stride (192 data + 8 zero pad)

typedef __attribute__((ext_vector_type(8))) short bf16x8;
typedef __attribute__((ext_vector_type(4))) float f32x4;

__device__ __forceinline__ unsigned short f2bf(float f) {
  unsigned int u = __float_as_uint(f);
  u += 0x7FFFu + ((u >> 16) & 1u);   // RNE
  return (unsigned short)(u >> 16);
}

// packed f32x2 -> bf16x2 (v_cvt_pk_bf16_f32 on gfx950)
__device__ __forceinline__ unsigned int pkbf(float a, float b) {
  __hip_bfloat162 h = __float22bfloat162_rn(make_float2(a, b));
  return *reinterpret_cast<unsigned int*>(&h);
}

// prep: z-normalize shapelets -> bf16 * (-2), B-fragment order grouped by
// CHANNEL (16 KB contiguous per c); init out to +inf. sum(z^2) == S == 64
// exactly (population z-norm) -> no per-k sqs needed. UNCHANGED since R1.
__global__ __launch_bounds__(256) void prep_kernel(const float* __restrict__ sh,
                                                   unsigned short* __restrict__ shzB,
                                                   float* __restrict__ out) {
  int tid = blockIdx.x * 256 + threadIdx.x;
  if (tid < NB * K) out[tid] = __int_as_float(0x7F800000);
  int gid = blockIdx.x * 4 + (threadIdx.x >> 6);  // c*K + k
  int lane = threadIdx.x & 63;                    // = s
  float v = sh[(size_t)gid * S + lane];
  float s1 = v, s2 = v * v;
#pragma unroll
  for (int off = 32; off > 0; off >>= 1) {
    s1 += __shfl_down(s1, off);
    s2 += __shfl_down(s2, off);
  }
  s1 = __shfl(s1, 0);
  s2 = __shfl(s2, 0);
  float mu = s1 * (1.0f / S);
  float sd = sqrtf(fmaxf(s2 * (1.0f / S) - mu * mu, 0.0f));
  float z = (v - mu) / sd;
  int c = gid >> 7, k = gid & (K - 1), s = lane;
  // layout: [c][k>>6][((k>>4)&3)*2 + (s>>5)][lane'=((s>>3)&3)*16+(k&15)][s&7]
  int idx = c * 8192 + (k >> 6) * 4096 + ((((k >> 4) & 3) * 2) + (s >> 5)) * 512 +
            ((((s >> 3) & 3) * 16 + (k & 15)) * 8) + (s & 7);
  shzB[idx] = f2bf(-2.0f * z);   // bake the -2 of d2 = (sqx + 64) - 2*cross
}

// One wt-subtile: 4 MFMAs (2 kt x 2 halves) into P[0..1] (all indices literal)
#define WT_COMPUTE(WT, P)                                                     \
  {                                                                           \
    bf16x8 x0 = *(const bf16x8*)(xc + abase + (WT) * 16);                     \
    bf16x8 x1 = *(const bf16x8*)(xc + abase + (WT) * 16 + 32);                \
    f32x4 ai = *(const f32x4*)&sqx[c][wgrp * 64 + (WT) * 16 + quad * 4];      \
    P[0] = __builtin_amdgcn_mfma_f32_16x16x32_bf16(x0, Bc[0], ai, 0, 0, 0);   \
    P[1] = __builtin_amdgcn_mfma_f32_16x16x32_bf16(x0, Bc[2], ai, 0, 0, 0);   \
    P[0] = __builtin_amdgcn_mfma_f32_16x16x32_bf16(x1, Bc[1], P[0], 0, 0, 0); \
    P[1] = __builtin_amdgcn_mfma_f32_16x16x32_bf16(x1, Bc[3], P[1], 0, 0, 0); \
  }

// trans epilogue of one wt-subtile (literal WT -> static dsum indexing)
#define WT_SQRT(WT, P)                                                        \
  {                                                                           \
    _Pragma("unroll")                                                         \
    for (int i = 0; i < 4; ++i) {                                             \
      dsum[0][WT][i] += __builtin_amdgcn_sqrtf(__builtin_fabsf(P[0][i]));     \
      dsum[1][WT][i] += __builtin_amdgcn_sqrtf(__builtin_fabsf(P[1][i]));     \
    }                                                                         \
  }

// main: block = 128w x 128k, 512 threads = 8 HOMOGENEOUS waves, wave tile
// 64w x 32k (wgrp = wave&1 -> w-half, kgrp = wave>>1 -> k-quarter).
// R9 post-mortem: producer/consumer split = 55us (trans pipe needs MANY
// sqrt-issuing waves, not few specialized ones) — reverted to homogeneous.
// R10 = R7's only-proven lever (live register state -> resident waves/SIMD)
// pushed via thread count, not geometry: same TW=128 block tile, same
// prologue pattern as R9 (proven clean), half the per-wave state
// (dsum[2][4]=32 + Bc[4]=16 + pA/pB=16 ~ 90-105 VGPR) -> ~5 waves/SIMD
// (vs R7's 3). launch_bounds(512,3) leaves VGPR slack (cap ~170) so the
// allocator is never forced into R8's spill corner. Channel-ring stagger
// retained (8 distinct wave phases/block). Arithmetic chain per output
// unchanged -> absmax 0.5. Tripwire: WRITE ~1MB, FETCH ~4MB (else spill).
__global__ __launch_bounds__(512, 3) void main_kernel(const float* __restrict__ x,
                                                      const unsigned short* __restrict__ shzB,
                                                      int* __restrict__ out) {
  __shared__ __align__(16) unsigned short xcop[C][8][XCS]; // 26 KB: 8 shifted copies
  __shared__ __align__(16) float sqx[C][TW];               // 4 KB (pre-biased +64)
  __shared__ __align__(16) float xf[C][XFS];               // 6.4 KB fp32 x scratch

  const int t = threadIdx.x;
  const int lane = t & 63;
  const int wave = t >> 6;     // 0..7
  const int wgrp = wave & 1;   // w-half: offset 64
  const int kgrp = wave >> 1;  // k-quarter 0..3: offset 32*kgrp
  const int col = lane & 15;
  const int quad = lane >> 4;
  const int n = blockIdx.y;
  const int w0 = blockIdx.x * TW;
  const float* xn = x + (size_t)n * C * L;
  // this wave's B-fragment stream: 4 x 1KB contiguous chunks per channel
  // (k-quarter kgrp = kblk kgrp>>1, kt-pair kgrp&1 within the kblk)
  const unsigned short* bw = shzB + (kgrp >> 1) * 4096 + (kgrp & 1) * 2048 + lane * 8;
  // phase-stagger start channel (wave-uniform SGPR; 8 distinct phases/block)
  const int cbase = (2 * wave + blockIdx.x + blockIdx.y) & 7;

  // ---- stage fp32 x segment into xf (1 ch/wave, float4/lane) ----
  float* xfp = &xf[0][0];
  {
    const int c = wave;
    const int e = lane * 4;
    float4 v; v.x = v.y = v.z = v.w = 0.0f;
    if (lane < 48) {
      int g = w0 + e;
      if (g + 3 < L) {
        v = *(const float4*)(xn + c * L + g);
      } else {  // last w-tile tail; feeds masked windows only
        v.x = (g + 0 < L) ? xn[c * L + g + 0] : 0.0f;
        v.y = (g + 1 < L) ? xn[c * L + g + 1] : 0.0f;
        v.z = (g + 2 < L) ? xn[c * L + g + 2] : 0.0f;
        v.w = (g + 3 < L) ? xn[c * L + g + 3] : 0.0f;
      }
    }
    if (lane < 50) *(float4*)&xfp[c * XFS + e] = v;   // lanes 48,49 zero-pad tail
  }
  __syncthreads();

  // ---- build 8 shifted bf16 copies (1 ch/wave; r=lane>>3; 12 dwords/lane) ----
  {
    const int cb = wave;
    const int rb = lane >> 3;         // 0..7
    const int c8 = lane & 7;
    const float* xr = xfp + cb * XFS;
#pragma unroll
    for (int j = 0; j < 12; ++j) {
      int i = (c8 + j * 8) * 2;       // 0..190 even
      *(unsigned int*)&xcop[cb][rb][i] = pkbf(xr[i + rb], xr[i + rb + 1]);
    }
  }
  // ---- sliding-window fp32 sqx (+64 bias = sum(z^2)): 1 ch/wave, 2 w/lane ----
  {
    const int c = wave, wl = lane * 2;
    const float* xr = xfp + c * XFS;
    float p0 = 0.f, p1 = 0.f, p2 = 0.f, p3 = 0.f;
#pragma unroll
    for (int si = 0; si < S; si += 4) {
      float v0 = xr[wl + si], v1 = xr[wl + si + 1], v2 = xr[wl + si + 2], v3 = xr[wl + si + 3];
      p0 = fmaf(v0, v0, p0); p1 = fmaf(v1, v1, p1);
      p2 = fmaf(v2, v2, p2); p3 = fmaf(v3, v3, p3);
    }
    float s0 = 64.0f + (p0 + p1) + (p2 + p3);
    sqx[c][wl] = s0;
    float a = xr[wl + S], b = xr[wl];
    sqx[c][wl + 1] = s0 + a * a - b * b;
  }
  __syncthreads();  // xcop + sqx ready; NO barriers after this point

  const f32x4 z4 = {0.0f, 0.0f, 0.0f, 0.0f};
  f32x4 dsum[2][4];   // [ktile][wtile]
#pragma unroll
  for (int kt = 0; kt < 2; ++kt)
#pragma unroll
    for (int wt = 0; wt < 4; ++wt) dsum[kt][wt] = z4;

  const int r8 = col & 7;
  const int abase = wgrp * 64 + (col - r8) + quad * 8;  // multiple of 8 -> b128 aligned

  for (int ci = 0; ci < C; ++ci) {
    const int c = (cbase + ci) & 7;   // wave-uniform (SGPR arithmetic)

    // B fragments for this channel's 32k quarter: 4 coalesced dwordx4 from L1/L2
    bf16x8 Bc[4];
#pragma unroll
    for (int i = 0; i < 4; ++i)
      Bc[i] = *(const bf16x8*)(bw + c * 8192 + i * 512);

    const unsigned short* xc = &xcop[c][r8][0];

    // wt-granularity alternation: MFMA(wt+1) drains while sqrt(wt) runs.
    f32x4 pA[2], pB[2];
    WT_COMPUTE(0, pA)
    WT_COMPUTE(1, pB)
    WT_SQRT(0, pA)
    WT_COMPUTE(2, pA)
    WT_SQRT(1, pB)
    WT_COMPUTE(3, pB)
    WT_SQRT(2, pA)
    WT_SQRT(3, pB)
  }

  // min over w (regs -> quad shuffles), one atomicMin per (k-tile, lane col)
  const float INF = __int_as_float(0x7F800000);
  const int wbase = w0 + wgrp * 64;
#pragma unroll
  for (int kt = 0; kt < 2; ++kt) {
    float mv = INF;
#pragma unroll
    for (int wt = 0; wt < 4; ++wt)
#pragma unroll
      for (int i = 0; i < 4; ++i) {
        int w = wbase + wt * 16 + quad * 4 + i;
        mv = (w < W) ? fminf(mv, dsum[kt][wt][i]) : mv;
      }
    mv = fminf(mv, __shfl_xor(mv, 16));
    mv = fminf(mv, __shfl_xor(mv, 32));
    if (quad == 0)
      atomicMin(&out[n * K + kgrp * 32 + kt * 16 + col], __float_as_int(mv));
  }
}

extern "C" void kernel_launch(void* const* d_in, const int* in_sizes, int n_in,
                              void* d_out, int out_size, void* d_ws, size_t ws_size,
                              hipStream_t stream) {
  const float* x = (const float*)d_in[0];    // (64, 8, 2048) fp32
  const float* sh = (const float*)d_in[1];   // (8, 128, 64) fp32
  float* out = (float*)d_out;                // (64, 1, 128) fp32
  unsigned short* shzB = (unsigned short*)d_ws;  // 128 KB bf16 B-frag layout (scaled -2)

  prep_kernel<<<256, 256, 0, stream>>>(sh, shzB, out);
  main_kernel<<<dim3(NTW, NB), 512, 0, stream>>>(x, shzB, (int*)out);
}

// Round 11
// 82.465 us; speedup vs baseline: 1.3310x; 1.1445x over previous
//
#include <hip/hip_runtime.h>
#include <hip/hip_bf16.h>
#include <math.h>

#define C 8
#define K 128
#define S 64
#define L 2048
#define NB 64
#define W (L - S + 1)   // 1985
#define TW 128
#define NTW 16
#define XCS 208         // xcop stride shorts: 104 dw = 8 banks mod 32 -> conflict-free b128
#define XFS 200         // fp32 x scratch stride (192 data + 8 zero pad)

typedef __attribute__((ext_vector_type(8))) short bf16x8;
typedef __attribute__((ext_vector_type(4))) float f32x4;

__device__ __forceinline__ unsigned short f2bf(float f) {
  unsigned int u = __float_as_uint(f);
  u += 0x7FFFu + ((u >> 16) & 1u);   // RNE
  return (unsigned short)(u >> 16);
}

// packed f32x2 -> bf16x2 (v_cvt_pk_bf16_f32 on gfx950)
__device__ __forceinline__ unsigned int pkbf(float a, float b) {
  __hip_bfloat162 h = __float22bfloat162_rn(make_float2(a, b));
  return *reinterpret_cast<unsigned int*>(&h);
}

// prep: z-normalize shapelets -> bf16 * (-2), B-fragment order grouped by
// CHANNEL (16 KB contiguous per c, both 64k halves inside); init out to +inf.
// sum(z^2) == S == 64 exactly (population z-norm) -> no per-k sqs needed.
__global__ __launch_bounds__(256) void prep_kernel(const float* __restrict__ sh,
                                                   unsigned short* __restrict__ shzB,
                                                   float* __restrict__ out) {
  int tid = blockIdx.x * 256 + threadIdx.x;
  if (tid < NB * K) out[tid] = __int_as_float(0x7F800000);
  int gid = blockIdx.x * 4 + (threadIdx.x >> 6);  // c*K + k
  int lane = threadIdx.x & 63;                    // = s
  float v = sh[(size_t)gid * S + lane];
  float s1 = v, s2 = v * v;
#pragma unroll
  for (int off = 32; off > 0; off >>= 1) {
    s1 += __shfl_down(s1, off);
    s2 += __shfl_down(s2, off);
  }
  s1 = __shfl(s1, 0);
  s2 = __shfl(s2, 0);
  float mu = s1 * (1.0f / S);
  float sd = sqrtf(fmaxf(s2 * (1.0f / S) - mu * mu, 0.0f));
  float z = (v - mu) / sd;
  int c = gid >> 7, k = gid & (K - 1), s = lane;
  // layout: [c][k>>6][((k>>4)&3)*2 + (s>>5)][lane'=((s>>3)&3)*16+(k&15)][s&7]
  int idx = c * 8192 + (k >> 6) * 4096 + ((((k >> 4) & 3) * 2) + (s >> 5)) * 512 +
            ((((s >> 3) & 3) * 16 + (k & 15)) * 8) + (s & 7);
  shzB[idx] = f2bf(-2.0f * z);   // bake the -2 of d2 = (sqx + 64) - 2*cross
}

// One wt-subtile: 8 MFMAs (4 kt x 2 halves) into P[0..3] (all indices literal)
#define WT_COMPUTE(WT, P)                                                     \
  {                                                                           \
    bf16x8 x0 = *(const bf16x8*)(xc + abase + (WT) * 16);                     \
    bf16x8 x1 = *(const bf16x8*)(xc + abase + (WT) * 16 + 32);                \
    f32x4 ai = *(const f32x4*)&sqx[c][wgrp * 64 + (WT) * 16 + quad * 4];      \
    P[0] = __builtin_amdgcn_mfma_f32_16x16x32_bf16(x0, Bc[0], ai, 0, 0, 0);   \
    P[1] = __builtin_amdgcn_mfma_f32_16x16x32_bf16(x0, Bc[2], ai, 0, 0, 0);   \
    P[2] = __builtin_amdgcn_mfma_f32_16x16x32_bf16(x0, Bc[4], ai, 0, 0, 0);   \
    P[3] = __builtin_amdgcn_mfma_f32_16x16x32_bf16(x0, Bc[6], ai, 0, 0, 0);   \
    P[0] = __builtin_amdgcn_mfma_f32_16x16x32_bf16(x1, Bc[1], P[0], 0, 0, 0); \
    P[1] = __builtin_amdgcn_mfma_f32_16x16x32_bf16(x1, Bc[3], P[1], 0, 0, 0); \
    P[2] = __builtin_amdgcn_mfma_f32_16x16x32_bf16(x1, Bc[5], P[2], 0, 0, 0); \
    P[3] = __builtin_amdgcn_mfma_f32_16x16x32_bf16(x1, Bc[7], P[3], 0, 0, 0); \
  }

// trans epilogue of one wt-subtile (literal WT -> static dsum indexing)
#define WT_SQRT(WT, P)                                                        \
  {                                                                           \
    _Pragma("unroll")                                                         \
    for (int i = 0; i < 4; ++i) {                                             \
      dsum[0][WT][i] += __builtin_amdgcn_sqrtf(__builtin_fabsf(P[0][i]));     \
      dsum[1][WT][i] += __builtin_amdgcn_sqrtf(__builtin_fabsf(P[1][i]));     \
      dsum[2][WT][i] += __builtin_amdgcn_sqrtf(__builtin_fabsf(P[2][i]));     \
      dsum[3][WT][i] += __builtin_amdgcn_sqrtf(__builtin_fabsf(P[3][i]));     \
    }                                                                         \
  }

// main: block = 128w x 128k, 256 threads = 4 waves, wave tile 64w x 64k.
// R11 = EXACT REVERT to R7, the session's measured best (main ~39us,
// bench 81.4us). Post-R7 experiments all regressed for mechanical reasons:
// R8 (64w geometry + tight VGPR cap) -> compiler scratch, 64MB fetch;
// R9 (producer/consumer waves) -> 55us, trans pipe needs many sqrt-issuing
// waves, not few specialized ones; R10 (512-thread homogeneous) -> partial
// spill (19MB writes) + occupancy quantization loss (1.5 blk/CU). The
// standing model: trans/VALU-issue-work dominated (~45K cyc/SIMD at ~50%
// feed); only proven lever = live-state reduction at FIXED geometry (R7's
// wt-granularity pA/pB alternation, 3 waves/SIMD); geometry and role
// changes are codegen-chaotic. Locking in the optimum.
// Structure: wt-alternation (compute wt0, wt1, sqrt wt0, compute wt2,
// sqrt wt1, compute wt3, sqrt wt2, sqrt wt3) covers mfma->sqrt latency
// with only 32 regs in flight; channel-ring stagger (cbase) decorrelates
// wave phases; fabs-as-modifier feeds v_sqrt's free input modifier.
__global__ __launch_bounds__(256, 3) void main_kernel(const float* __restrict__ x,
                                                      const unsigned short* __restrict__ shzB,
                                                      int* __restrict__ out) {
  __shared__ __align__(16) unsigned short xcop[C][8][XCS]; // 26 KB: 8 shifted copies
  __shared__ __align__(16) float sqx[C][TW];               // 4 KB (pre-biased +64)
  __shared__ __align__(16) float xf[C][XFS];               // 6.4 KB fp32 x scratch

  const int t = threadIdx.x;
  const int lane = t & 63;
  const int wave = t >> 6;     // 0..3
  const int wgrp = wave & 1;   // w-offset 64
  const int kgrp = wave >> 1;  // 0..1 : k-offset 64*kgrp
  const int col = lane & 15;
  const int quad = lane >> 4;
  const int n = blockIdx.y;
  const int w0 = blockIdx.x * TW;
  const float* xn = x + (size_t)n * C * L;
  // this wave's B-fragment stream: 8 x 1KB contiguous chunks per channel
  const unsigned short* bw = shzB + kgrp * 4096 + lane * 8;
  // phase-stagger start channel (wave-uniform SGPR; decorrelates waves/blocks)
  const int cbase = (2 * wave + blockIdx.x + blockIdx.y) & 7;

  // ---- stage fp32 x segment into xf (2 ch/wave, float4/lane) ----
  float* xfp = &xf[0][0];
#pragma unroll
  for (int cc = 0; cc < 2; ++cc) {
    const int c = wave * 2 + cc;
    const int e = lane * 4;
    float4 v; v.x = v.y = v.z = v.w = 0.0f;
    if (lane < 48) {
      int g = w0 + e;
      if (g + 3 < L) {
        v = *(const float4*)(xn + c * L + g);
      } else {  // last w-tile tail; feeds masked windows only
        v.x = (g + 0 < L) ? xn[c * L + g + 0] : 0.0f;
        v.y = (g + 1 < L) ? xn[c * L + g + 1] : 0.0f;
        v.z = (g + 2 < L) ? xn[c * L + g + 2] : 0.0f;
        v.w = (g + 3 < L) ? xn[c * L + g + 3] : 0.0f;
      }
    }
    if (lane < 50) *(float4*)&xfp[c * XFS + e] = v;   // lanes 48,49 zero-pad tail
  }
  __syncthreads();

  // ---- build 8 shifted bf16 copies (2 ch/wave; r=lane>>3; 12 dwords/lane/ch) ----
#pragma unroll
  for (int cc = 0; cc < 2; ++cc) {
    const int cb = wave * 2 + cc;
    const int rb = lane >> 3;         // 0..7
    const int c8 = lane & 7;
    const float* xr = xfp + cb * XFS;
#pragma unroll
    for (int j = 0; j < 12; ++j) {
      int i = (c8 + j * 8) * 2;       // 0..190 even
      *(unsigned int*)&xcop[cb][rb][i] = pkbf(xr[i + rb], xr[i + rb + 1]);
    }
  }
  // ---- sliding-window fp32 sqx (+64 bias = sum(z^2)): 2 ch/wave, 2 w/lane ----
#pragma unroll
  for (int cc = 0; cc < 2; ++cc) {
    const int c = wave * 2 + cc, wl = lane * 2;
    const float* xr = xfp + c * XFS;
    float p0 = 0.f, p1 = 0.f, p2 = 0.f, p3 = 0.f;
#pragma unroll
    for (int si = 0; si < S; si += 4) {
      float v0 = xr[wl + si], v1 = xr[wl + si + 1], v2 = xr[wl + si + 2], v3 = xr[wl + si + 3];
      p0 = fmaf(v0, v0, p0); p1 = fmaf(v1, v1, p1);
      p2 = fmaf(v2, v2, p2); p3 = fmaf(v3, v3, p3);
    }
    float s0 = 64.0f + (p0 + p1) + (p2 + p3);
    sqx[c][wl] = s0;
    float a = xr[wl + S], b = xr[wl];
    sqx[c][wl + 1] = s0 + a * a - b * b;
  }
  __syncthreads();  // xcop + sqx ready; NO barriers after this point

  const f32x4 z4 = {0.0f, 0.0f, 0.0f, 0.0f};
  f32x4 dsum[4][4];   // [ktile][wtile]
#pragma unroll
  for (int kt = 0; kt < 4; ++kt)
#pragma unroll
    for (int wt = 0; wt < 4; ++wt) dsum[kt][wt] = z4;

  const int r8 = col & 7;
  const int abase = wgrp * 64 + (col - r8) + quad * 8;  // multiple of 8 -> b128 aligned

  for (int ci = 0; ci < C; ++ci) {
    const int c = (cbase + ci) & 7;   // wave-uniform (SGPR arithmetic)

    // B fragments for this channel: 8 coalesced dwordx4 from L1/L2
    bf16x8 Bc[8];
#pragma unroll
    for (int i = 0; i < 8; ++i)
      Bc[i] = *(const bf16x8*)(bw + c * 8192 + i * 512);

    const unsigned short* xc = &xcop[c][r8][0];

    // wt-granularity alternation: MFMA(wt+1) drains while sqrt(wt) runs.
    // Only 32 regs of accumulator-in-flight state (vs 64 channel-level).
    f32x4 pA[4], pB[4];
    WT_COMPUTE(0, pA)
    WT_COMPUTE(1, pB)
    WT_SQRT(0, pA)
    WT_COMPUTE(2, pA)
    WT_SQRT(1, pB)
    WT_COMPUTE(3, pB)
    WT_SQRT(2, pA)
    WT_SQRT(3, pB)
  }

  // min over w (regs -> quad shuffles), one atomicMin per (k-tile, lane col)
  const float INF = __int_as_float(0x7F800000);
  const int wbase = w0 + wgrp * 64;
#pragma unroll
  for (int kt = 0; kt < 4; ++kt) {
    float mv = INF;
#pragma unroll
    for (int wt = 0; wt < 4; ++wt)
#pragma unroll
      for (int i = 0; i < 4; ++i) {
        int w = wbase + wt * 16 + quad * 4 + i;
        mv = (w < W) ? fminf(mv, dsum[kt][wt][i]) : mv;
      }
    mv = fminf(mv, __shfl_xor(mv, 16));
    mv = fminf(mv, __shfl_xor(mv, 32));
    if (quad == 0)
      atomicMin(&out[n * K + kgrp * 64 + kt * 16 + col], __float_as_int(mv));
  }
}

extern "C" void kernel_launch(void* const* d_in, const int* in_sizes, int n_in,
                              void* d_out, int out_size, void* d_ws, size_t ws_size,
                              hipStream_t stream) {
  const float* x = (const float*)d_in[0];    // (64, 8, 2048) fp32
  const float* sh = (const float*)d_in[1];   // (8, 128, 64) fp32
  float* out = (float*)d_out;                // (64, 1, 128) fp32
  unsigned short* shzB = (unsigned short*)d_ws;  // 128 KB bf16 B-frag layout (scaled -2)

  prep_kernel<<<256, 256, 0, stream>>>(sh, shzB, out);
  main_kernel<<<dim3(NTW, NB), 256, 0, stream>>>(x, shzB, (int*)out);
}